// Round 8
// baseline (311.124 us; speedup 1.0000x reference)
//
#include <hip/hip_runtime.h>

typedef __attribute__((ext_vector_type(8))) short bf16x8;
typedef __attribute__((ext_vector_type(4))) float f32x4;

constexpr int BROWS  = 131072;
constexpr int DDIM   = 128;
constexpr int NTILES = BROWS / 16;   // 8192 row-tiles
constexpr int GRID   = 2048;         // 4 tiles per block

__device__ __forceinline__ short to_bf16(float f) {
    unsigned u = __builtin_bit_cast(unsigned, f);
    u = (u + 0x7FFFu + ((u >> 16) & 1u)) >> 16;   // RTNE
    return (short)u;
}

__device__ __forceinline__ bf16x8 cvt8(f32x4 lo, f32x4 hi) {
    bf16x8 r;
#pragma unroll
    for (int i = 0; i < 4; ++i) { r[i] = to_bf16(lo[i]); r[i + 4] = to_bf16(hi[i]); }
    return r;
}

// ---------- Probe A: R1 front-end (loads + cvt + MFMA), NO stores ----------
__global__ void __launch_bounds__(256)
probe_load(const float* __restrict__ state, const float* __restrict__ W) {
    const int lane = threadIdx.x & 63;
    const int wave = threadIdx.x >> 6;
    const int l16  = lane & 15;
    const int lq   = lane >> 4;

    bf16x8 wfrag[4][4];
#pragma unroll
    for (int ct = 0; ct < 4; ++ct) {
        const int c = wave * 64 + ct * 16 + l16;
        const float* wrow = W + (c & 127) * 256 + (c >> 7) * 128;
#pragma unroll
        for (int ks = 0; ks < 4; ++ks) {
            f32x4 lo = *reinterpret_cast<const f32x4*>(wrow + ks * 32 + lq * 8);
            f32x4 hi = *reinterpret_cast<const f32x4*>(wrow + ks * 32 + lq * 8 + 4);
            wfrag[ct][ks] = cvt8(lo, hi);
        }
    }

    for (int t = blockIdx.x; t < NTILES; t += GRID) {
        const float* srow = state + (size_t)(t * 16 + l16) * DDIM + lq * 8;
        f32x4 raw[8];
#pragma unroll
        for (int ks = 0; ks < 4; ++ks) {
            raw[2 * ks]     = *reinterpret_cast<const f32x4*>(srow + ks * 32);
            raw[2 * ks + 1] = *reinterpret_cast<const f32x4*>(srow + ks * 32 + 4);
        }
        bf16x8 af[4];
#pragma unroll
        for (int ks = 0; ks < 4; ++ks) af[ks] = cvt8(raw[2 * ks], raw[2 * ks + 1]);
#pragma unroll
        for (int ct = 0; ct < 4; ++ct) {
            f32x4 acc = {0.f, 0.f, 0.f, 0.f};
#pragma unroll
            for (int ks = 0; ks < 4; ++ks)
                acc = __builtin_amdgcn_mfma_f32_16x16x32_bf16(af[ks], wfrag[ct][ks], acc, 0, 0, 0);
            // keep alive without storing (rule #17)
            asm volatile("" :: "v"(acc[0]), "v"(acc[1]), "v"(acc[2]), "v"(acc[3]));
        }
    }
}

// ---------- Probe B: ideal lane-contiguous streaming stores (131 MB) ----------
__global__ void __launch_bounds__(256)
probe_stlin(float* __restrict__ out) {
    const f32x4 v = {1.f, 2.f, 3.f, 4.f};
    const size_t gtid = (size_t)blockIdx.x * 256 + threadIdx.x;
    const size_t tot  = (size_t)GRID * 256;
#pragma unroll
    for (int it = 0; it < 16; ++it)
        *reinterpret_cast<f32x4*>(out + ((size_t)it * tot + gtid) * 4) = v;
}

// ---------- Probe C: R1's scattered MFMA-layout store pattern (131 MB) ----------
__global__ void __launch_bounds__(256)
probe_stseg(float* __restrict__ out) {
    const int lane = threadIdx.x & 63;
    const int wave = threadIdx.x >> 6;
    const int l16  = lane & 15;
    const int lq   = lane >> 4;
    const float v  = (float)(l16 + lq);

    for (int t = blockIdx.x; t < NTILES; t += GRID) {
#pragma unroll
        for (int ct = 0; ct < 4; ++ct) {
            const int c = wave * 64 + ct * 16 + l16;
            const size_t row = (size_t)t * 16 + lq * 4;
            float* dst = out + ((c < 128)
                                ? (row * 128 + c)
                                : ((size_t)BROWS * 128 + row * 128 + (c - 128)));
#pragma unroll
            for (int r = 0; r < 4; ++r)
                dst[(size_t)r * 128] = v;
        }
    }
}

// ---------- Full kernel: R1 compute + LDS-staged linear-store epilogue ----------
__global__ void __launch_bounds__(256)
lfm_kernel(const float* __restrict__ state, const float* __restrict__ W,
           const float* __restrict__ bias, float* __restrict__ out) {
    const int lane = threadIdx.x & 63;
    const int wave = threadIdx.x >> 6;
    const int l16  = lane & 15;
    const int lq   = lane >> 4;

    __shared__ float lds[2 * 16 * 132];   // [plane][row][col], pad 132 vs 128

    bf16x8 wfrag[4][4];
    float  biasr[4];
#pragma unroll
    for (int ct = 0; ct < 4; ++ct) {
        const int c = wave * 64 + ct * 16 + l16;
        const int n = c & 127, o = c >> 7;
        const float* wrow = W + n * 256 + o * 128;
        biasr[ct] = bias[n * 2 + o];
#pragma unroll
        for (int ks = 0; ks < 4; ++ks) {
            f32x4 lo = *reinterpret_cast<const f32x4*>(wrow + ks * 32 + lq * 8);
            f32x4 hi = *reinterpret_cast<const f32x4*>(wrow + ks * 32 + lq * 8 + 4);
            wfrag[ct][ks] = cvt8(lo, hi);
        }
    }

    const int p    = wave >> 1;          // output plane this wave feeds
    const int colw = (wave & 1) * 64;    // col base within the plane

    for (int t = blockIdx.x; t < NTILES; t += GRID) {
        const float* srow = state + (size_t)(t * 16 + l16) * DDIM + lq * 8;
        f32x4 raw[8];
#pragma unroll
        for (int ks = 0; ks < 4; ++ks) {
            raw[2 * ks]     = *reinterpret_cast<const f32x4*>(srow + ks * 32);
            raw[2 * ks + 1] = *reinterpret_cast<const f32x4*>(srow + ks * 32 + 4);
        }
        bf16x8 af[4];
#pragma unroll
        for (int ks = 0; ks < 4; ++ks) af[ks] = cvt8(raw[2 * ks], raw[2 * ks + 1]);

#pragma unroll
        for (int ct = 0; ct < 4; ++ct) {
            f32x4 acc = {biasr[ct], biasr[ct], biasr[ct], biasr[ct]};
#pragma unroll
            for (int ks = 0; ks < 4; ++ks)
                acc = __builtin_amdgcn_mfma_f32_16x16x32_bf16(af[ks], wfrag[ct][ks], acc, 0, 0, 0);
            // D layout: b-row = lq*4 + r, col = l16  ->  stage into LDS
            const int col = colw + ct * 16 + l16;
#pragma unroll
            for (int r = 0; r < 4; ++r)
                lds[(p * 16 + lq * 4 + r) * 132 + col] = acc[r];
        }
        __syncthreads();
        // linear drain: 16 KiB tile -> two 8-KiB contiguous global regions
#pragma unroll
        for (int j = 0; j < 4; ++j) {
            const int flat = j * 1024 + threadIdx.x * 4;   // float index, 0..4095
            const int pp   = flat >> 11;                    // plane
            const int row  = (flat >> 7) & 15;
            f32x4 v = *reinterpret_cast<f32x4*>(&lds[(pp * 16 + row) * 132 + (flat & 127)]);
            *reinterpret_cast<f32x4*>(out + (size_t)pp * BROWS * 128
                                          + (size_t)t * 2048 + (flat & 2047)) = v;
        }
        __syncthreads();
    }
}

extern "C" void kernel_launch(void* const* d_in, const int* in_sizes, int n_in,
                              void* d_out, int out_size, void* d_ws, size_t ws_size,
                              hipStream_t stream) {
    const float* state = (const float*)d_in[0];
    const float* W     = (const float*)d_in[1];
    const float* bias  = (const float*)d_in[2];
    float* out = (float*)d_out;

    // Probes first (their output is scratch / overwritten), correct kernel LAST.
    hipLaunchKernelGGL(probe_load,  dim3(GRID), dim3(256), 0, stream, state, W);
    hipLaunchKernelGGL(probe_stlin, dim3(GRID), dim3(256), 0, stream, out);
    hipLaunchKernelGGL(probe_stseg, dim3(GRID), dim3(256), 0, stream, out);
    hipLaunchKernelGGL(lfm_kernel,  dim3(GRID), dim3(256), 0, stream, state, W, bias, out);
}

// Round 9
// 219.669 us; speedup vs baseline: 1.4163x; 1.4163x over previous
//
#include <hip/hip_runtime.h>

typedef __attribute__((ext_vector_type(8))) short bf16x8;
typedef __attribute__((ext_vector_type(4))) float f32x4;

constexpr int BROWS  = 131072;
constexpr int DDIM   = 128;
constexpr int NTILES = BROWS / 16;   // 8192 row-tiles
constexpr int GRID   = 2048;         // 4 tiles per block

__device__ __forceinline__ short to_bf16(float f) {
    unsigned u = __builtin_bit_cast(unsigned, f);
    u = (u + 0x7FFFu + ((u >> 16) & 1u)) >> 16;   // RTNE
    return (short)u;
}

__device__ __forceinline__ bf16x8 cvt8(f32x4 lo, f32x4 hi) {
    bf16x8 r;
#pragma unroll
    for (int i = 0; i < 4; ++i) { r[i] = to_bf16(lo[i]); r[i + 4] = to_bf16(hi[i]); }
    return r;
}

// R1 compute front-end + LDS-staged linear-store epilogue.
//  MFMA D layout: col = l16 (b-row), row = lq*4+r (output col per this wave's
//  ct-tile) -> scatter into padded LDS [plane][row][col], then drain the
//  16-row x 128-col x 2-plane tile as two contiguous 8-KiB global regions
//  (each wave stores 1 KiB per instruction).
__global__ void __launch_bounds__(256)
lfm_kernel(const float* __restrict__ state, const float* __restrict__ W,
           const float* __restrict__ bias, float* __restrict__ out) {
    const int lane = threadIdx.x & 63;
    const int wave = threadIdx.x >> 6;
    const int l16  = lane & 15;
    const int lq   = lane >> 4;

    __shared__ float lds[2 * 16 * 132];   // [plane][row][col], pad 132 vs 128

    bf16x8 wfrag[4][4];
    float  biasr[4];
#pragma unroll
    for (int ct = 0; ct < 4; ++ct) {
        const int c = wave * 64 + ct * 16 + l16;
        const int n = c & 127, o = c >> 7;
        const float* wrow = W + n * 256 + o * 128;
        biasr[ct] = bias[n * 2 + o];
#pragma unroll
        for (int ks = 0; ks < 4; ++ks) {
            f32x4 lo = *reinterpret_cast<const f32x4*>(wrow + ks * 32 + lq * 8);
            f32x4 hi = *reinterpret_cast<const f32x4*>(wrow + ks * 32 + lq * 8 + 4);
            wfrag[ct][ks] = cvt8(lo, hi);
        }
    }

    for (int t = blockIdx.x; t < NTILES; t += GRID) {
        const float* srow = state + (size_t)(t * 16 + l16) * DDIM + lq * 8;
        f32x4 raw[8];
#pragma unroll
        for (int ks = 0; ks < 4; ++ks) {
            raw[2 * ks]     = *reinterpret_cast<const f32x4*>(srow + ks * 32);
            raw[2 * ks + 1] = *reinterpret_cast<const f32x4*>(srow + ks * 32 + 4);
        }
        bf16x8 af[4];
#pragma unroll
        for (int ks = 0; ks < 4; ++ks) af[ks] = cvt8(raw[2 * ks], raw[2 * ks + 1]);

#pragma unroll
        for (int ct = 0; ct < 4; ++ct) {
            f32x4 acc = {biasr[ct], biasr[ct], biasr[ct], biasr[ct]};
#pragma unroll
            for (int ks = 0; ks < 4; ++ks)
                acc = __builtin_amdgcn_mfma_f32_16x16x32_bf16(af[ks], wfrag[ct][ks], acc, 0, 0, 0);
            const int c   = wave * 64 + ct * 16 + l16;   // global col 0..255
            const int p   = c >> 7;                      // plane
            const int col = c & 127;
#pragma unroll
            for (int r = 0; r < 4; ++r)
                lds[(p * 16 + lq * 4 + r) * 132 + col] = acc[r];
        }
        __syncthreads();
        // linear drain: 16 KiB tile -> two 8-KiB contiguous global regions
#pragma unroll
        for (int j = 0; j < 4; ++j) {
            const int flat = j * 1024 + threadIdx.x * 4;   // float idx 0..4095
            const int pp   = flat >> 11;                   // plane
            const int row  = (flat >> 7) & 15;
            f32x4 v = *reinterpret_cast<f32x4*>(&lds[(pp * 16 + row) * 132 + (flat & 127)]);
            *reinterpret_cast<f32x4*>(out + (size_t)pp * BROWS * 128
                                          + (size_t)t * 2048 + (flat & 2047)) = v;
        }
        __syncthreads();
    }
}

extern "C" void kernel_launch(void* const* d_in, const int* in_sizes, int n_in,
                              void* d_out, int out_size, void* d_ws, size_t ws_size,
                              hipStream_t stream) {
    const float* state = (const float*)d_in[0];
    const float* W     = (const float*)d_in[1];
    const float* bias  = (const float*)d_in[2];
    float* out = (float*)d_out;
    hipLaunchKernelGGL(lfm_kernel, dim3(GRID), dim3(256), 0, stream,
                       state, W, bias, out);
}